// Round 6
// baseline (17588.092 us; speedup 1.0000x reference)
//
#include <hip/hip_runtime.h>
#include <math.h>

#define BB 32
#define SS 512
#define EE 256
#define HH 512
#define VV 32000
#define TT 30
#define WPE 772   // LDS weight row pitch (768 data + 4 pad), 16B-aligned rows

__device__ __forceinline__ float4 ldf4(const float* p) {
    return *reinterpret_cast<const float4*>(p);
}
__device__ __forceinline__ float dot4(float4 a, float4 b) {
    return a.x * b.x + a.y * b.y + a.z * b.z + a.w * b.w;
}
__device__ __forceinline__ float sigmoidf_(float x) {
    return 1.0f / (1.0f + expf(-x));
}
__device__ __forceinline__ void fma4(float4& a, float s, const float4& b) {
    a.x = fmaf(s, b.x, a.x); a.y = fmaf(s, b.y, a.y);
    a.z = fmaf(s, b.z, a.z); a.w = fmaf(s, b.w, a.w);
}
__device__ __forceinline__ unsigned long long mkkey(float val, int v) {
    unsigned u = __float_as_uint(val);
    u = (u >> 31) ? ~u : (u | 0x80000000u);
    return ((unsigned long long)u << 32) | (0xFFFFFFFFu - (unsigned)v);
}
__device__ __forceinline__ unsigned long long sxmax(unsigned long long k, int m) {
    unsigned hi = (unsigned)(k >> 32), lo = (unsigned)k;
    unsigned oh = __shfl_xor(hi, m), ol = __shfl_xor(lo, m);
    unsigned long long o = ((unsigned long long)oh << 32) | ol;
    return o > k ? o : k;
}

// Flag-array barrier: per-member release store, parallel poll (no same-address
// RMW contention). fl = base of this barrier group's flags, stride 32 words.
__device__ __forceinline__ void gbar(unsigned* fl, int me, int n, int tid,
                                     unsigned tgt) {
    __syncthreads();
    if (tid == 0)
        __hip_atomic_store(fl + (size_t)me * 32, tgt, __ATOMIC_RELEASE,
                           __HIP_MEMORY_SCOPE_AGENT);
    if (tid < n) {
        while (__hip_atomic_load(fl + (size_t)tid * 32, __ATOMIC_RELAXED,
                                 __HIP_MEMORY_SCOPE_AGENT) < tgt)
            __builtin_amdgcn_s_sleep(2);
    }
    __syncthreads();
    __builtin_amdgcn_fence(__ATOMIC_ACQUIRE, "agent");
}

// NOTE: parameter must NOT be named `w` — the preprocessor would also
// substitute the member token in `W.w`.
#define GATE4(acc0, acc1, W, h00, h01, h10, h11, h20, h21, h30, h31) \
    fma4(acc0, W.x, h00); fma4(acc1, W.x, h01);                      \
    fma4(acc0, W.y, h10); fma4(acc1, W.y, h11);                      \
    fma4(acc0, W.z, h20); fma4(acc1, W.z, h21);                      \
    fma4(acc0, W.w, h30); fma4(acc1, W.w, h31);

#define XR4(vv, m) { vv.x += __shfl_xor(vv.x, m); vv.y += __shfl_xor(vv.y, m); \
                     vv.z += __shfl_xor(vv.z, m); vv.w += __shfl_xor(vv.w, m); }

// ---------------------------------------------------------------------------
// Persistent encoder v2. grid = 256 x 256, 1 block/CU (LDS-bound).
// Domain d = bid&7 = (dir, bgroup of 8 batch); member m = bid>>3 owns 16 j.
// Batch independence => barrier only among the 32 blocks of a domain.
// Weights (16j x 3g x 768k) LDS-resident. h per domain: hD[d][parity][512k][8b].
// Thread (ks=tid>>4, jl=tid&15): 8-b float4-pair accumulators over k-slice;
// intra-wave shfl_xor reduce over ks, 2-stage LDS combine, 128 finalize.
// ---------------------------------------------------------------------------
__global__ __launch_bounds__(256, 1) void enc_persist2(
    const int* __restrict__ body,
    const float* __restrict__ enc_emb,
    const float* __restrict__ wih_f, const float* __restrict__ whh_f,
    const float* __restrict__ bih_f, const float* __restrict__ bhh_f,
    const float* __restrict__ wih_b, const float* __restrict__ whh_b,
    const float* __restrict__ bih_b, const float* __restrict__ bhh_b,
    float* __restrict__ hD,          // [8][2][512][8]
    unsigned* __restrict__ flagE)    // [8][32] stride-32 flags
{
    const int bid = blockIdx.x;
    const int tid = threadIdx.x;
    const int d   = bid & 7;
    const int m   = bid >> 3;        // j-chunk: j in [m*16, m*16+16)
    const int dir = d >> 2;
    const int bg  = d & 3;           // batch rows [bg*8, bg*8+8)
    const int jc  = m;

    const float* wih = dir ? wih_b : wih_f;
    const float* whh = dir ? whh_b : whh_f;
    const float* bih = dir ? bih_b : bih_f;
    const float* bhh = dir ? bhh_b : bhh_f;

    __shared__ float wlds[16 * 3 * WPE];   // 148,224 B
    __shared__ float xlds[256 * 8];        //   8,192 B  [k][b]
    __shared__ float part[2][16][33];      //   4,224 B
    __shared__ float blds[16][4];

    // ---- one-time: weights -> LDS (48 rows x 192 quads) ----
    for (int idx = tid; idx < 48 * 192; idx += 256) {
        const int row = idx / 192;          // jl*3 + g
        const int q   = idx - row * 192;
        const int jl0 = row / 3, g = row - jl0 * 3;
        const int k   = q * 4;
        const int grow = g * HH + jc * 16 + jl0;
        float4 v = (k < HH) ? ldf4(whh + (size_t)grow * HH + k)
                            : ldf4(wih + (size_t)grow * EE + (k - HH));
        float* dst = wlds + row * WPE + k;
        dst[0] = v.x; dst[1] = v.y; dst[2] = v.z; dst[3] = v.w;
    }
    if (tid < 16) {
        const int jg = jc * 16 + tid;
        blds[tid][0] = bih[jg] + bhh[jg];
        blds[tid][1] = bih[jg + HH] + bhh[jg + HH];
        blds[tid][2] = bih[jg + 2 * HH];   // b_in
        blds[tid][3] = bhh[jg + 2 * HH];   // b_hn
    }
    __syncthreads();

    const int ks   = tid >> 4;      // 0..15 k-split
    const int jl   = tid & 15;      // local j
    const int lane = tid & 63;
    const int wv   = tid >> 6;      // wave 0..3
    const float* wj = wlds + (jl * 3) * WPE;
    float* hdom = hD + (size_t)d * 2 * 4096;
    unsigned* fdom = flagE + (size_t)d * 1024;

    for (int t = 0; t < SS; ++t) {
        const int p = t & 1;

        // ---- stage x (transposed) ----
        {
            const int sb = tid & 7, kc = tid >> 3;   // kc 0..31
            const int bglob = bg * 8 + sb;
            const int s = dir ? (SS - 1 - t) : t;
            const int tk = body[bglob * SS + s];
            const float* xr = enc_emb + (size_t)tk * EE + kc * 8;
            float4 v0 = ldf4(xr), v1 = ldf4(xr + 4);
            const int k0 = kc * 8;
            xlds[(k0 + 0) * 8 + sb] = v0.x; xlds[(k0 + 1) * 8 + sb] = v0.y;
            xlds[(k0 + 2) * 8 + sb] = v0.z; xlds[(k0 + 3) * 8 + sb] = v0.w;
            xlds[(k0 + 4) * 8 + sb] = v1.x; xlds[(k0 + 5) * 8 + sb] = v1.y;
            xlds[(k0 + 6) * 8 + sb] = v1.z; xlds[(k0 + 7) * 8 + sb] = v1.w;
        }
        __syncthreads();

        const float* hp = hdom + p * 4096;
        float4 aR0 = {0,0,0,0}, aR1 = {0,0,0,0};
        float4 aZ0 = {0,0,0,0}, aZ1 = {0,0,0,0};
        float4 aN0 = {0,0,0,0}, aN1 = {0,0,0,0};   // h-part of gate n
        float4 aI0 = {0,0,0,0}, aI1 = {0,0,0,0};   // x-part of gate n

        // ---- h-part: k in [ks*32, ks*32+32) ----
        #pragma unroll
        for (int q = 0; q < 8; ++q) {
            const int k = ks * 32 + q * 4;
            float4 wr = ldf4(wj + 0 * WPE + k);
            float4 wz = ldf4(wj + 1 * WPE + k);
            float4 wn = ldf4(wj + 2 * WPE + k);
            const float* hk = hp + k * 8;
            float4 h00 = ldf4(hk +  0), h01 = ldf4(hk +  4);
            float4 h10 = ldf4(hk +  8), h11 = ldf4(hk + 12);
            float4 h20 = ldf4(hk + 16), h21 = ldf4(hk + 20);
            float4 h30 = ldf4(hk + 24), h31 = ldf4(hk + 28);
            GATE4(aR0, aR1, wr, h00, h01, h10, h11, h20, h21, h30, h31);
            GATE4(aZ0, aZ1, wz, h00, h01, h10, h11, h20, h21, h30, h31);
            GATE4(aN0, aN1, wn, h00, h01, h10, h11, h20, h21, h30, h31);
        }
        // ---- x-part: k in [ks*16, ks*16+16) ----
        #pragma unroll
        for (int q = 0; q < 4; ++q) {
            const int k = ks * 16 + q * 4;
            float4 wr = ldf4(wj + 0 * WPE + HH + k);
            float4 wz = ldf4(wj + 1 * WPE + HH + k);
            float4 wn = ldf4(wj + 2 * WPE + HH + k);
            const float* xk = xlds + k * 8;
            float4 x00 = ldf4(xk +  0), x01 = ldf4(xk +  4);
            float4 x10 = ldf4(xk +  8), x11 = ldf4(xk + 12);
            float4 x20 = ldf4(xk + 16), x21 = ldf4(xk + 20);
            float4 x30 = ldf4(xk + 24), x31 = ldf4(xk + 28);
            GATE4(aR0, aR1, wr, x00, x01, x10, x11, x20, x21, x30, x31);
            GATE4(aZ0, aZ1, wz, x00, x01, x10, x11, x20, x21, x30, x31);
            GATE4(aI0, aI1, wn, x00, x01, x10, x11, x20, x21, x30, x31);
        }

        // ---- reduce ks within wave (lanes differ in ks bits 0..1) ----
        XR4(aR0, 16); XR4(aR0, 32); XR4(aR1, 16); XR4(aR1, 32);
        XR4(aZ0, 16); XR4(aZ0, 32); XR4(aZ1, 16); XR4(aZ1, 32);
        XR4(aN0, 16); XR4(aN0, 32); XR4(aN1, 16); XR4(aN1, 32);
        XR4(aI0, 16); XR4(aI0, 32); XR4(aI1, 16); XR4(aI1, 32);

        // ---- 2-stage cross-wave combine ----
        if (wv < 2 && (lane >> 4) == 0) {
            float* pr = &part[wv][jl][0];
            pr[ 0]=aR0.x; pr[ 1]=aR0.y; pr[ 2]=aR0.z; pr[ 3]=aR0.w;
            pr[ 4]=aR1.x; pr[ 5]=aR1.y; pr[ 6]=aR1.z; pr[ 7]=aR1.w;
            pr[ 8]=aZ0.x; pr[ 9]=aZ0.y; pr[10]=aZ0.z; pr[11]=aZ0.w;
            pr[12]=aZ1.x; pr[13]=aZ1.y; pr[14]=aZ1.z; pr[15]=aZ1.w;
            pr[16]=aN0.x; pr[17]=aN0.y; pr[18]=aN0.z; pr[19]=aN0.w;
            pr[20]=aN1.x; pr[21]=aN1.y; pr[22]=aN1.z; pr[23]=aN1.w;
            pr[24]=aI0.x; pr[25]=aI0.y; pr[26]=aI0.z; pr[27]=aI0.w;
            pr[28]=aI1.x; pr[29]=aI1.y; pr[30]=aI1.z; pr[31]=aI1.w;
        }
        __syncthreads();
        if (wv >= 2 && (lane >> 4) == 0) {
            float* pr = &part[wv - 2][jl][0];
            pr[ 0]+=aR0.x; pr[ 1]+=aR0.y; pr[ 2]+=aR0.z; pr[ 3]+=aR0.w;
            pr[ 4]+=aR1.x; pr[ 5]+=aR1.y; pr[ 6]+=aR1.z; pr[ 7]+=aR1.w;
            pr[ 8]+=aZ0.x; pr[ 9]+=aZ0.y; pr[10]+=aZ0.z; pr[11]+=aZ0.w;
            pr[12]+=aZ1.x; pr[13]+=aZ1.y; pr[14]+=aZ1.z; pr[15]+=aZ1.w;
            pr[16]+=aN0.x; pr[17]+=aN0.y; pr[18]+=aN0.z; pr[19]+=aN0.w;
            pr[20]+=aN1.x; pr[21]+=aN1.y; pr[22]+=aN1.z; pr[23]+=aN1.w;
            pr[24]+=aI0.x; pr[25]+=aI0.y; pr[26]+=aI0.z; pr[27]+=aI0.w;
            pr[28]+=aI1.x; pr[29]+=aI1.y; pr[30]+=aI1.z; pr[31]+=aI1.w;
        }
        __syncthreads();

        // ---- finalize: 128 threads, one (jl,b) each ----
        if (tid < 128) {
            const int j2 = tid >> 3, b = tid & 7;
            float sR = part[0][j2][b]      + part[1][j2][b]      + blds[j2][0];
            float sZ = part[0][j2][8 + b]  + part[1][j2][8 + b]  + blds[j2][1];
            float sN = part[0][j2][16 + b] + part[1][j2][16 + b] + blds[j2][3];
            float sI = part[0][j2][24 + b] + part[1][j2][24 + b] + blds[j2][2];
            const float r = sigmoidf_(sR);
            const float z = sigmoidf_(sZ);
            const float n = tanhf(sI + r * sN);
            const int jg = jc * 16 + j2;
            const float hold = hp[jg * 8 + b];
            hdom[(p ^ 1) * 4096 + jg * 8 + b] = (1.0f - z) * n + z * hold;
        }

        if (t < SS - 1)
            gbar(fdom, m, 32, tid, (unsigned)(t + 1));
        else
            __syncthreads();
    }
}

// hidden (transposed [k][b]) = h_fwd + h_bwd (parity 0 after 512 steps)
__global__ __launch_bounds__(256) void enc_fin(
    const float* __restrict__ hD, float* __restrict__ hdT)
{
    const int i = blockIdx.x * 256 + threadIdx.x;   // 0 .. 512*32-1
    const int k = i >> 5, b = i & 31;
    const int bg = b >> 3, sb = b & 7;
    hdT[i] = hD[(size_t)bg * 8192 + k * 8 + sb]
           + hD[(size_t)(4 + bg) * 8192 + k * 8 + sb];
}

// ---------------------------------------------------------------------------
// Persistent decoder v2. grid = 256 x 1024 (16 waves/CU), no LDS weights.
// Per step: [tok from prev cand, all blocks] -> stage x -> Phase A (GRU,
// block owns 2 j-rows, 16-way k-split via LDS) -> barrier -> Phase B
// (125 v/block, thread = 1 v x 4 b, streams fc_w with 16 waves of MLP,
// wave+LDS argmax reduce -> cand[bid][b]) -> barrier.
// ---------------------------------------------------------------------------
__global__ __launch_bounds__(1024, 4) void dec_persist2(
    const float* __restrict__ dec_emb,
    const float* __restrict__ wih, const float* __restrict__ whh,
    const float* __restrict__ bih, const float* __restrict__ bhh,
    const float* __restrict__ fc_w, const float* __restrict__ fc_b,
    float* __restrict__ hdT,                 // [2][512][32]
    float* __restrict__ hdrow,               // [32][512]
    unsigned long long* __restrict__ cand,   // [256][32]
    float* __restrict__ out,                 // [32][30][32000]
    unsigned* __restrict__ flagD)            // [256] stride-32 flags
{
    const int bid = blockIdx.x;
    const int tid = threadIdx.x;

    __shared__ float xls[256 * 32];                 // 32,768  [k][b]
    __shared__ float partD[16][64][4];              // 16,384
    __shared__ unsigned long long lwred[16][8][4];  //  4,096
    __shared__ unsigned long long candp[32][33];    //  8,448
    __shared__ int tokL[32];

    // phase-A finalize biases (tid<64: b=tid>>1, jl=tid&1)
    float bR = 0, bZ = 0, bI = 0, bN = 0;
    if (tid < 64) {
        const int j2 = bid * 2 + (tid & 1);
        bR = bih[j2] + bhh[j2];
        bZ = bih[j2 + HH] + bhh[j2 + HH];
        bI = bih[j2 + 2 * HH];
        bN = bhh[j2 + 2 * HH];
    }

    for (int t = 0; t < TT; ++t) {
        const int p = t & 1;

        // ---- token from previous step's candidates ----
        if (t == 0) {
            if (tid < 32) tokL[tid] = 1;   // BOS
        } else {
            const int b = tid & 31, cc = tid >> 5;
            if (cc < 32) {
                unsigned long long km = 0ull;
                #pragma unroll
                for (int i = 0; i < 8; ++i) {
                    unsigned long long k2 = cand[(size_t)(cc * 8 + i) * 32 + b];
                    if (k2 > km) km = k2;
                }
                candp[cc][b] = km;
            }
            __syncthreads();
            if (tid < 32) {
                unsigned long long m2 = candp[0][tid];
                for (int c2 = 1; c2 < 32; ++c2) {
                    unsigned long long k2 = candp[c2][tid];
                    if (k2 > m2) m2 = k2;
                }
                tokL[tid] = (int)(0xFFFFFFFFu - (unsigned)(m2 & 0xFFFFFFFFull));
            }
        }
        __syncthreads();

        // ---- stage x (transposed [k][b]) ----
        if (tid < 1024) {
            const int b = tid & 31, kc = tid >> 5;   // kc 0..31
            const float* xr = dec_emb + (size_t)tokL[b] * EE + kc * 8;
            float4 v0 = ldf4(xr), v1 = ldf4(xr + 4);
            const int k0 = kc * 8;
            xls[(k0 + 0) * 32 + b] = v0.x; xls[(k0 + 1) * 32 + b] = v0.y;
            xls[(k0 + 2) * 32 + b] = v0.z; xls[(k0 + 3) * 32 + b] = v0.w;
            xls[(k0 + 4) * 32 + b] = v1.x; xls[(k0 + 5) * 32 + b] = v1.y;
            xls[(k0 + 6) * 32 + b] = v1.z; xls[(k0 + 7) * 32 + b] = v1.w;
        }
        __syncthreads();

        // ---- Phase A: GRU h-update (block owns j = bid*2 + {0,1}) ----
        {
            const int ks = tid >> 6, b = (tid >> 1) & 31, jl = tid & 1;
            const int j = bid * 2 + jl;
            float sR = 0.f, sZ = 0.f, sN = 0.f, sI = 0.f;
            const float* hp = hdT + (size_t)p * HH * BB;
            const float* wr_h = whh + (size_t)j            * HH;
            const float* wz_h = whh + (size_t)(j + HH)     * HH;
            const float* wn_h = whh + (size_t)(j + 2 * HH) * HH;
            #pragma unroll
            for (int q = 0; q < 8; ++q) {
                const int k = ks * 32 + q * 4;
                float4 wr = ldf4(wr_h + k), wz = ldf4(wz_h + k), wn = ldf4(wn_h + k);
                float h0 = hp[(k + 0) * 32 + b], h1 = hp[(k + 1) * 32 + b];
                float h2 = hp[(k + 2) * 32 + b], h3 = hp[(k + 3) * 32 + b];
                sR = fmaf(wr.x, h0, fmaf(wr.y, h1, fmaf(wr.z, h2, fmaf(wr.w, h3, sR))));
                sZ = fmaf(wz.x, h0, fmaf(wz.y, h1, fmaf(wz.z, h2, fmaf(wz.w, h3, sZ))));
                sN = fmaf(wn.x, h0, fmaf(wn.y, h1, fmaf(wn.z, h2, fmaf(wn.w, h3, sN))));
            }
            const float* wr_i = wih + (size_t)j            * EE;
            const float* wz_i = wih + (size_t)(j + HH)     * EE;
            const float* wn_i = wih + (size_t)(j + 2 * HH) * EE;
            #pragma unroll
            for (int q = 0; q < 4; ++q) {
                const int k = ks * 16 + q * 4;
                float4 wr = ldf4(wr_i + k), wz = ldf4(wz_i + k), wn = ldf4(wn_i + k);
                float x0 = xls[(k + 0) * 32 + b], x1 = xls[(k + 1) * 32 + b];
                float x2 = xls[(k + 2) * 32 + b], x3 = xls[(k + 3) * 32 + b];
                sR = fmaf(wr.x, x0, fmaf(wr.y, x1, fmaf(wr.z, x2, fmaf(wr.w, x3, sR))));
                sZ = fmaf(wz.x, x0, fmaf(wz.y, x1, fmaf(wz.z, x2, fmaf(wz.w, x3, sZ))));
                sI = fmaf(wn.x, x0, fmaf(wn.y, x1, fmaf(wn.z, x2, fmaf(wn.w, x3, sI))));
            }
            float* pd = &partD[ks][b * 2 + jl][0];
            pd[0] = sR; pd[1] = sZ; pd[2] = sN; pd[3] = sI;
        }
        __syncthreads();
        if (tid < 64) {
            const int b = tid >> 1, jl = tid & 1;
            const int j = bid * 2 + jl;
            float sR = bR, sZ = bZ, sN = bN, sI = bI;
            #pragma unroll
            for (int q2 = 0; q2 < 16; ++q2) {
                sR += partD[q2][tid][0]; sZ += partD[q2][tid][1];
                sN += partD[q2][tid][2]; sI += partD[q2][tid][3];
            }
            const float r = sigmoidf_(sR);
            const float z = sigmoidf_(sZ);
            const float n = tanhf(sI + r * sN);
            const float hold = hdT[(size_t)p * HH * BB + j * 32 + b];
            const float hnew = (1.0f - z) * n + z * hold;
            hdT[(size_t)(p ^ 1) * HH * BB + j * 32 + b] = hnew;
            hdrow[(size_t)b * HH + j] = hnew;
        }

        gbar(flagD, bid, 256, tid, (unsigned)(2 * t + 1));

        // ---- Phase B: logits (125 v per block) + argmax candidates ----
        {
            const int vt = tid >> 3, bh = tid & 7;
            const int v = bid * 125 + vt;
            const bool alive = (vt < 125);
            float a0 = 0.f, a1 = 0.f, a2 = 0.f, a3 = 0.f;
            if (alive) {
                const float* wv_ = fc_w + (size_t)v * HH;
                const float* h0r = hdrow + (size_t)(bh * 4 + 0) * HH;
                const float* h1r = hdrow + (size_t)(bh * 4 + 1) * HH;
                const float* h2r = hdrow + (size_t)(bh * 4 + 2) * HH;
                const float* h3r = hdrow + (size_t)(bh * 4 + 3) * HH;
                #pragma unroll 2
                for (int k = 0; k < HH; k += 8) {
                    float4 w0 = ldf4(wv_ + k), w1 = ldf4(wv_ + k + 4);
                    float4 p0 = ldf4(h0r + k), q0 = ldf4(h0r + k + 4);
                    float4 p1 = ldf4(h1r + k), q1 = ldf4(h1r + k + 4);
                    float4 p2 = ldf4(h2r + k), q2 = ldf4(h2r + k + 4);
                    float4 p3 = ldf4(h3r + k), q3 = ldf4(h3r + k + 4);
                    a0 += dot4(w0, p0) + dot4(w1, q0);
                    a1 += dot4(w0, p1) + dot4(w1, q1);
                    a2 += dot4(w0, p2) + dot4(w1, q2);
                    a3 += dot4(w0, p3) + dot4(w1, q3);
                }
                const float fb = fc_b[v];
                a0 += fb; a1 += fb; a2 += fb; a3 += fb;
                out[((size_t)((bh * 4 + 0) * TT + t)) * VV + v] = a0;
                out[((size_t)((bh * 4 + 1) * TT + t)) * VV + v] = a1;
                out[((size_t)((bh * 4 + 2) * TT + t)) * VV + v] = a2;
                out[((size_t)((bh * 4 + 3) * TT + t)) * VV + v] = a3;
            }
            unsigned long long k0 = alive ? mkkey(a0, v) : 0ull;
            unsigned long long k1 = alive ? mkkey(a1, v) : 0ull;
            unsigned long long k2 = alive ? mkkey(a2, v) : 0ull;
            unsigned long long k3 = alive ? mkkey(a3, v) : 0ull;
            // reduce across vt within wave (vt bits = lane>>3)
            #pragma unroll
            for (int msk = 8; msk <= 32; msk <<= 1) {
                k0 = sxmax(k0, msk); k1 = sxmax(k1, msk);
                k2 = sxmax(k2, msk); k3 = sxmax(k3, msk);
            }
            if ((tid & 56) == 0) {   // one lane per (wave, bh)
                lwred[tid >> 6][bh][0] = k0; lwred[tid >> 6][bh][1] = k1;
                lwred[tid >> 6][bh][2] = k2; lwred[tid >> 6][bh][3] = k3;
            }
        }
        __syncthreads();
        if (tid < 32) {   // b = tid; bh = b>>2, i = b&3
            unsigned long long km = lwred[0][tid >> 2][tid & 3];
            #pragma unroll
            for (int w2 = 1; w2 < 16; ++w2) {
                unsigned long long k2 = lwred[w2][tid >> 2][tid & 3];
                if (k2 > km) km = k2;
            }
            cand[(size_t)bid * 32 + tid] = km;
        }

        if (t < TT - 1)
            gbar(flagD, bid, 256, tid, (unsigned)(2 * t + 2));
    }
}

// ---------------------------------------------------------------------------
extern "C" void kernel_launch(void* const* d_in, const int* in_sizes, int n_in,
                              void* d_out, int out_size, void* d_ws, size_t ws_size,
                              hipStream_t stream) {
    (void)in_sizes; (void)n_in; (void)out_size; (void)ws_size;

    const int*   body    = (const int*)  d_in[0];
    const float* enc_emb = (const float*)d_in[2];
    const float* wih_f   = (const float*)d_in[3];
    const float* whh_f   = (const float*)d_in[4];
    const float* bih_f   = (const float*)d_in[5];
    const float* bhh_f   = (const float*)d_in[6];
    const float* wih_b   = (const float*)d_in[7];
    const float* whh_b   = (const float*)d_in[8];
    const float* bih_b   = (const float*)d_in[9];
    const float* bhh_b   = (const float*)d_in[10];
    const float* dec_emb = (const float*)d_in[11];
    const float* dwih    = (const float*)d_in[12];
    const float* dwhh    = (const float*)d_in[13];
    const float* dbih    = (const float*)d_in[14];
    const float* dbhh    = (const float*)d_in[15];
    const float* fc_w    = (const float*)d_in[16];
    const float* fc_b    = (const float*)d_in[17];
    float* out = (float*)d_out;

    char* ws = (char*)d_ws;
    float* hD    = (float*)(ws);                    // [8][2][512][8]  = 262,144 B
    float* hdT   = (float*)(ws + 262144);           // [2][512][32]    = 131,072 B
    float* hdrow = (float*)(ws + 393216);           // [32][512]       =  65,536 B
    unsigned long long* cand =
        (unsigned long long*)(ws + 458752);         // [256][32]       =  65,536 B
    unsigned* flagE = (unsigned*)(ws + 524288);     // 8*32*128B       =  32,768 B
    unsigned* flagD = (unsigned*)(ws + 557056);     // 256*128B        =  32,768 B

    // re-init cross-call state (graph-replay safe)
    (void)hipMemsetAsync(hD, 0, 262144, stream);    // h parity buffers
    (void)hipMemsetAsync(flagE, 0, 65536, stream);  // flagE + flagD (contiguous)

    enc_persist2<<<256, 256, 0, stream>>>(
        body, enc_emb, wih_f, whh_f, bih_f, bhh_f,
        wih_b, whh_b, bih_b, bhh_b, hD, flagE);

    enc_fin<<<64, 256, 0, stream>>>(hD, hdT);

    dec_persist2<<<256, 1024, 0, stream>>>(
        dec_emb, dwih, dwhh, dbih, dbhh, fc_w, fc_b,
        hdT, hdrow, cand, out, flagD);
}

// Round 7
// 6290.446 us; speedup vs baseline: 2.7960x; 2.7960x over previous
//
#include <hip/hip_runtime.h>
#include <math.h>

#define BB 32
#define SS 512
#define EE 256
#define HH 512
#define VV 32000
#define TT 30
#define WPH 516   // LDS whh row pitch (512 data + 4 pad)

typedef unsigned long long ull;

__device__ __forceinline__ float4 ldf4(const float* p) {
    return *reinterpret_cast<const float4*>(p);
}
__device__ __forceinline__ float sigmoidf_(float x) {
    return 1.0f / (1.0f + expf(-x));
}
__device__ __forceinline__ void fma4(float4& a, float s, const float4& b) {
    a.x = fmaf(s, b.x, a.x); a.y = fmaf(s, b.y, a.y);
    a.z = fmaf(s, b.z, a.z); a.w = fmaf(s, b.w, a.w);
}
__device__ __forceinline__ ull mkkey(float val, int v) {
    unsigned u = __float_as_uint(val);
    u = (u >> 31) ? ~u : (u | 0x80000000u);
    return ((ull)u << 32) | (0xFFFFFFFFu - (unsigned)v);
}
__device__ __forceinline__ ull sxmax(ull k, int m) {
    unsigned hi = (unsigned)(k >> 32), lo = (unsigned)k;
    unsigned oh = __shfl_xor(hi, m), ol = __shfl_xor(lo, m);
    ull o = ((ull)oh << 32) | ol;
    return o > k ? o : k;
}
__device__ __forceinline__ ull cld8(const ull* p) {   // coherent 8B load
    return __hip_atomic_load(p, __ATOMIC_RELAXED, __HIP_MEMORY_SCOPE_AGENT);
}
__device__ __forceinline__ void cst4(float* p, float v) {  // coherent 4B store
    __hip_atomic_store(p, v, __ATOMIC_RELAXED, __HIP_MEMORY_SCOPE_AGENT);
}

// Flag-array barrier, NO acquire fence (no L2 invalidation). All cross-block
// data goes through relaxed agent-scope atomics (individually coherent).
// __syncthreads drains every wave's vmcnt before the release store.
__device__ __forceinline__ void gbar(unsigned* fl, int me, int n, int tid,
                                     unsigned tgt) {
    __syncthreads();
    if (tid == 0)
        __hip_atomic_store(fl + (size_t)me * 32, tgt, __ATOMIC_RELEASE,
                           __HIP_MEMORY_SCOPE_AGENT);
    if (tid < n) {
        while (__hip_atomic_load(fl + (size_t)tid * 32, __ATOMIC_RELAXED,
                                 __HIP_MEMORY_SCOPE_AGENT) < tgt)
            __builtin_amdgcn_s_sleep(2);
    }
    __syncthreads();
}

#define GATE4(acc0, acc1, W, h00, h01, h10, h11, h20, h21, h30, h31) \
    fma4(acc0, W.x, h00); fma4(acc1, W.x, h01);                      \
    fma4(acc0, W.y, h10); fma4(acc1, W.y, h11);                      \
    fma4(acc0, W.z, h20); fma4(acc1, W.z, h21);                      \
    fma4(acc0, W.w, h30); fma4(acc1, W.w, h31);

#define XR4(vv, m) { vv.x += __shfl_xor(vv.x, m); vv.y += __shfl_xor(vv.y, m); \
                     vv.z += __shfl_xor(vv.z, m); vv.w += __shfl_xor(vv.w, m); }

// ---------------------------------------------------------------------------
// Persistent encoder v3. grid = 256 x 256, 1 block/CU.
// Domain d = bid&7 = (dir, bgroup of 8); member m = bid>>3 owns 16 j.
// whh slice in LDS; wih slice read from (now永-warm) L2; h_prev staged into
// LDS each step via coherent 8B loads; h_new written via coherent 4B stores.
// ---------------------------------------------------------------------------
__global__ __launch_bounds__(256, 1) void enc_persist3(
    const int* __restrict__ body,
    const float* __restrict__ enc_emb,
    const float* __restrict__ wih_f, const float* __restrict__ whh_f,
    const float* __restrict__ bih_f, const float* __restrict__ bhh_f,
    const float* __restrict__ wih_b, const float* __restrict__ whh_b,
    const float* __restrict__ bih_b, const float* __restrict__ bhh_b,
    float* __restrict__ hD,          // [8][2][512][8]
    unsigned* __restrict__ flagE)    // [8][32] stride-32 flags
{
    const int bid = blockIdx.x;
    const int tid = threadIdx.x;
    const int d   = bid & 7;
    const int m   = bid >> 3;
    const int dir = d >> 2;
    const int bg  = d & 3;
    const int jc  = m;

    const float* wih = dir ? wih_b : wih_f;
    const float* whh = dir ? whh_b : whh_f;
    const float* bih = dir ? bih_b : bih_f;
    const float* bhh = dir ? bhh_b : bhh_f;

    __shared__ float wlds[16 * 3 * WPH];   //  99,072 B (whh only)
    __shared__ float hlds[512 * 8];        //  16,384 B  [k][8b]
    __shared__ float xlds[256 * 8];        //   8,192 B  [k][8b]
    __shared__ float part[2][16][33];      //   4,224 B
    __shared__ float blds[16][4];

    // ---- one-time: whh slice -> LDS (48 rows x 128 quads) ----
    for (int idx = tid; idx < 48 * 128; idx += 256) {
        const int row = idx >> 7;          // jl*3 + g
        const int q   = idx & 127;
        const int jl0 = row / 3, g = row - jl0 * 3;
        const int k   = q * 4;
        float4 v = ldf4(whh + (size_t)(g * HH + jc * 16 + jl0) * HH + k);
        float* dst = wlds + row * WPH + k;
        dst[0] = v.x; dst[1] = v.y; dst[2] = v.z; dst[3] = v.w;
    }
    if (tid < 16) {
        const int jg = jc * 16 + tid;
        blds[tid][0] = bih[jg] + bhh[jg];
        blds[tid][1] = bih[jg + HH] + bhh[jg + HH];
        blds[tid][2] = bih[jg + 2 * HH];   // b_in
        blds[tid][3] = bhh[jg + 2 * HH];   // b_hn
    }

    const int ks   = tid >> 4;
    const int jl   = tid & 15;
    const int jg   = jc * 16 + jl;
    const int lane = tid & 63;
    const int wv   = tid >> 6;
    const float* wj = wlds + (jl * 3) * WPH;
    const float* wr_i = wih + (size_t)jg            * EE;
    const float* wz_i = wih + (size_t)(jg + HH)     * EE;
    const float* wn_i = wih + (size_t)(jg + 2 * HH) * EE;
    float* hdom = hD + (size_t)d * 2 * 4096;
    unsigned* fdom = flagE + (size_t)d * 1024;

    for (int t = 0; t < SS; ++t) {
        const int p = t & 1;

        // ---- stage h_prev (coherent) + x (plain) into LDS ----
        {
            const ull* hsU = (const ull*)(hdom + p * 4096);
            ull hv[8];
            #pragma unroll
            for (int i = 0; i < 8; ++i) hv[i] = cld8(hsU + tid * 8 + i);
            ull* hlU = (ull*)hlds;
            #pragma unroll
            for (int i = 0; i < 8; ++i) hlU[tid * 8 + i] = hv[i];
        }
        {
            const int sb = tid & 7, kc = tid >> 3;
            const int s = dir ? (SS - 1 - t) : t;
            const int tk = body[(bg * 8 + sb) * SS + s];
            const float* xr = enc_emb + (size_t)tk * EE + kc * 8;
            float4 v0 = ldf4(xr), v1 = ldf4(xr + 4);
            const int k0 = kc * 8;
            xlds[(k0 + 0) * 8 + sb] = v0.x; xlds[(k0 + 1) * 8 + sb] = v0.y;
            xlds[(k0 + 2) * 8 + sb] = v0.z; xlds[(k0 + 3) * 8 + sb] = v0.w;
            xlds[(k0 + 4) * 8 + sb] = v1.x; xlds[(k0 + 5) * 8 + sb] = v1.y;
            xlds[(k0 + 6) * 8 + sb] = v1.z; xlds[(k0 + 7) * 8 + sb] = v1.w;
        }
        __syncthreads();

        float4 aR0 = {0,0,0,0}, aR1 = {0,0,0,0};
        float4 aZ0 = {0,0,0,0}, aZ1 = {0,0,0,0};
        float4 aN0 = {0,0,0,0}, aN1 = {0,0,0,0};
        float4 aI0 = {0,0,0,0}, aI1 = {0,0,0,0};

        // ---- h-part: k in [ks*32, ks*32+32), weights from LDS ----
        #pragma unroll
        for (int q = 0; q < 8; ++q) {
            const int k = ks * 32 + q * 4;
            float4 wr = ldf4(wj + 0 * WPH + k);
            float4 wz = ldf4(wj + 1 * WPH + k);
            float4 wn = ldf4(wj + 2 * WPH + k);
            const float* hk = hlds + k * 8;
            float4 h00 = ldf4(hk +  0), h01 = ldf4(hk +  4);
            float4 h10 = ldf4(hk +  8), h11 = ldf4(hk + 12);
            float4 h20 = ldf4(hk + 16), h21 = ldf4(hk + 20);
            float4 h30 = ldf4(hk + 24), h31 = ldf4(hk + 28);
            GATE4(aR0, aR1, wr, h00, h01, h10, h11, h20, h21, h30, h31);
            GATE4(aZ0, aZ1, wz, h00, h01, h10, h11, h20, h21, h30, h31);
            GATE4(aN0, aN1, wn, h00, h01, h10, h11, h20, h21, h30, h31);
        }
        // ---- x-part: k in [ks*16, ks*16+16), weights from L2 (plain) ----
        #pragma unroll
        for (int q = 0; q < 4; ++q) {
            const int k = ks * 16 + q * 4;
            float4 wr = ldf4(wr_i + k);
            float4 wz = ldf4(wz_i + k);
            float4 wn = ldf4(wn_i + k);
            const float* xk = xlds + k * 8;
            float4 x00 = ldf4(xk +  0), x01 = ldf4(xk +  4);
            float4 x10 = ldf4(xk +  8), x11 = ldf4(xk + 12);
            float4 x20 = ldf4(xk + 16), x21 = ldf4(xk + 20);
            float4 x30 = ldf4(xk + 24), x31 = ldf4(xk + 28);
            GATE4(aR0, aR1, wr, x00, x01, x10, x11, x20, x21, x30, x31);
            GATE4(aZ0, aZ1, wz, x00, x01, x10, x11, x20, x21, x30, x31);
            GATE4(aI0, aI1, wn, x00, x01, x10, x11, x20, x21, x30, x31);
        }

        XR4(aR0, 16); XR4(aR0, 32); XR4(aR1, 16); XR4(aR1, 32);
        XR4(aZ0, 16); XR4(aZ0, 32); XR4(aZ1, 16); XR4(aZ1, 32);
        XR4(aN0, 16); XR4(aN0, 32); XR4(aN1, 16); XR4(aN1, 32);
        XR4(aI0, 16); XR4(aI0, 32); XR4(aI1, 16); XR4(aI1, 32);

        if (wv < 2 && (lane >> 4) == 0) {
            float* pr = &part[wv][jl][0];
            pr[ 0]=aR0.x; pr[ 1]=aR0.y; pr[ 2]=aR0.z; pr[ 3]=aR0.w;
            pr[ 4]=aR1.x; pr[ 5]=aR1.y; pr[ 6]=aR1.z; pr[ 7]=aR1.w;
            pr[ 8]=aZ0.x; pr[ 9]=aZ0.y; pr[10]=aZ0.z; pr[11]=aZ0.w;
            pr[12]=aZ1.x; pr[13]=aZ1.y; pr[14]=aZ1.z; pr[15]=aZ1.w;
            pr[16]=aN0.x; pr[17]=aN0.y; pr[18]=aN0.z; pr[19]=aN0.w;
            pr[20]=aN1.x; pr[21]=aN1.y; pr[22]=aN1.z; pr[23]=aN1.w;
            pr[24]=aI0.x; pr[25]=aI0.y; pr[26]=aI0.z; pr[27]=aI0.w;
            pr[28]=aI1.x; pr[29]=aI1.y; pr[30]=aI1.z; pr[31]=aI1.w;
        }
        __syncthreads();
        if (wv >= 2 && (lane >> 4) == 0) {
            float* pr = &part[wv - 2][jl][0];
            pr[ 0]+=aR0.x; pr[ 1]+=aR0.y; pr[ 2]+=aR0.z; pr[ 3]+=aR0.w;
            pr[ 4]+=aR1.x; pr[ 5]+=aR1.y; pr[ 6]+=aR1.z; pr[ 7]+=aR1.w;
            pr[ 8]+=aZ0.x; pr[ 9]+=aZ0.y; pr[10]+=aZ0.z; pr[11]+=aZ0.w;
            pr[12]+=aZ1.x; pr[13]+=aZ1.y; pr[14]+=aZ1.z; pr[15]+=aZ1.w;
            pr[16]+=aN0.x; pr[17]+=aN0.y; pr[18]+=aN0.z; pr[19]+=aN0.w;
            pr[20]+=aN1.x; pr[21]+=aN1.y; pr[22]+=aN1.z; pr[23]+=aN1.w;
            pr[24]+=aI0.x; pr[25]+=aI0.y; pr[26]+=aI0.z; pr[27]+=aI0.w;
            pr[28]+=aI1.x; pr[29]+=aI1.y; pr[30]+=aI1.z; pr[31]+=aI1.w;
        }
        __syncthreads();

        if (tid < 128) {
            const int j2 = tid >> 3, b = tid & 7;
            float sR = part[0][j2][b]      + part[1][j2][b]      + blds[j2][0];
            float sZ = part[0][j2][8 + b]  + part[1][j2][8 + b]  + blds[j2][1];
            float sN = part[0][j2][16 + b] + part[1][j2][16 + b] + blds[j2][3];
            float sI = part[0][j2][24 + b] + part[1][j2][24 + b] + blds[j2][2];
            const float r = sigmoidf_(sR);
            const float z = sigmoidf_(sZ);
            const float n = tanhf(sI + r * sN);
            const int jw = jc * 16 + j2;
            const float hold = hlds[jw * 8 + b];
            cst4(hdom + (p ^ 1) * 4096 + jw * 8 + b, (1.0f - z) * n + z * hold);
        }

        if (t < SS - 1)
            gbar(fdom, m, 32, tid, (unsigned)(t + 1));
        else
            __syncthreads();
    }
}

// hidden (transposed [k][b]) = h_fwd + h_bwd (parity 0 after 512 steps)
__global__ __launch_bounds__(256) void enc_fin(
    const float* __restrict__ hD, float* __restrict__ hdT)
{
    const int i = blockIdx.x * 256 + threadIdx.x;
    const int k = i >> 5, b = i & 31;
    const int bg = b >> 3, sb = b & 7;
    hdT[i] = hD[(size_t)bg * 8192 + k * 8 + sb]
           + hD[(size_t)(4 + bg) * 8192 + k * 8 + sb];
}

// ---------------------------------------------------------------------------
// Persistent decoder v3. grid = 256 x 1024, 1 block/CU.
// Per step: tok-reduce (coherent cand) -> stage x -> A: GRU (h from hlds,
// weights from warm L2) -> coherent h stores -> bar -> stage h (coherent)
// -> B: logits 4v x 4b x 4ks per thread (16 waves stream fc_w from warm
// L2/L3/HBM, shfl ks-reduce) -> cand coherent stores -> bar.
// ---------------------------------------------------------------------------
__global__ __launch_bounds__(1024, 4) void dec_persist3(
    const float* __restrict__ dec_emb,
    const float* __restrict__ wih, const float* __restrict__ whh,
    const float* __restrict__ bih, const float* __restrict__ bhh,
    const float* __restrict__ fc_w, const float* __restrict__ fc_b,
    const float* __restrict__ hdT,           // [512][32] encoder hidden
    float* __restrict__ hdG,                 // [512][32] exchange buffer
    ull* __restrict__ cand,                  // [256][32]
    float* __restrict__ out,                 // [32][30][32000]
    unsigned* __restrict__ flagD)            // [256] stride-32 flags
{
    const int bid = blockIdx.x;
    const int tid = threadIdx.x;

    __shared__ float hlds[512 * 32];        // 65,536  [k][b]
    __shared__ float xls[256 * 32];         // 32,768  [k][b]
    __shared__ float partD[16][64][4];      // 16,384
    __shared__ ull lwred[16][8][4];         //  4,096
    __shared__ ull candp[32][33];           //  8,448
    __shared__ int tokL[32];

    // biases for phase-A finalize (tid<64: b=tid>>1, jl=tid&1)
    float bR = 0, bZ = 0, bI = 0, bN = 0;
    if (tid < 64) {
        const int j2 = bid * 2 + (tid & 1);
        bR = bih[j2] + bhh[j2];
        bZ = bih[j2 + HH] + bhh[j2 + HH];
        bI = bih[j2 + 2 * HH];
        bN = bhh[j2 + 2 * HH];
    }

    // prologue: stage encoder hidden -> hlds (plain; enc_fin flushed at exit)
    for (int i = tid; i < 4096; i += 1024) {
        *(float4*)(hlds + i * 4) = ldf4(hdT + i * 4);
    }

    for (int t = 0; t < TT; ++t) {
        // ---- token from previous step's candidates (coherent) ----
        if (t == 0) {
            if (tid < 32) tokL[tid] = 1;   // BOS
        } else {
            {
                const int b = tid & 31, cc = tid >> 5;
                ull km = 0ull;
                #pragma unroll
                for (int i = 0; i < 8; ++i) {
                    ull k2 = cld8(cand + (size_t)(cc * 8 + i) * 32 + b);
                    if (k2 > km) km = k2;
                }
                candp[cc][b] = km;
            }
            __syncthreads();
            if (tid < 32) {
                ull m2 = candp[0][tid];
                for (int c2 = 1; c2 < 32; ++c2) {
                    ull k2 = candp[c2][tid];
                    if (k2 > m2) m2 = k2;
                }
                tokL[tid] = (int)(0xFFFFFFFFu - (unsigned)(m2 & 0xFFFFFFFFull));
            }
        }
        __syncthreads();

        // ---- stage x (plain, [k][b]) ----
        {
            const int b = tid & 31, kc = tid >> 5;
            const float* xr = dec_emb + (size_t)tokL[b] * EE + kc * 8;
            float4 v0 = ldf4(xr), v1 = ldf4(xr + 4);
            const int k0 = kc * 8;
            xls[(k0 + 0) * 32 + b] = v0.x; xls[(k0 + 1) * 32 + b] = v0.y;
            xls[(k0 + 2) * 32 + b] = v0.z; xls[(k0 + 3) * 32 + b] = v0.w;
            xls[(k0 + 4) * 32 + b] = v1.x; xls[(k0 + 5) * 32 + b] = v1.y;
            xls[(k0 + 6) * 32 + b] = v1.z; xls[(k0 + 7) * 32 + b] = v1.w;
        }
        __syncthreads();

        // ---- Phase A: GRU h-update (block owns j = bid*2 + {0,1}) ----
        {
            const int ks = tid >> 6, b = (tid >> 1) & 31, jl = tid & 1;
            const int j = bid * 2 + jl;
            float sR = 0.f, sZ = 0.f, sN = 0.f, sI = 0.f;
            const float* wr_h = whh + (size_t)j            * HH;
            const float* wz_h = whh + (size_t)(j + HH)     * HH;
            const float* wn_h = whh + (size_t)(j + 2 * HH) * HH;
            #pragma unroll
            for (int q = 0; q < 8; ++q) {
                const int k = ks * 32 + q * 4;
                float4 wr = ldf4(wr_h + k), wz = ldf4(wz_h + k), wn = ldf4(wn_h + k);
                float h0 = hlds[(k + 0) * 32 + b], h1 = hlds[(k + 1) * 32 + b];
                float h2 = hlds[(k + 2) * 32 + b], h3 = hlds[(k + 3) * 32 + b];
                sR = fmaf(wr.x, h0, fmaf(wr.y, h1, fmaf(wr.z, h2, fmaf(wr.w, h3, sR))));
                sZ = fmaf(wz.x, h0, fmaf(wz.y, h1, fmaf(wz.z, h2, fmaf(wz.w, h3, sZ))));
                sN = fmaf(wn.x, h0, fmaf(wn.y, h1, fmaf(wn.z, h2, fmaf(wn.w, h3, sN))));
            }
            const float* wr_x = wih + (size_t)j            * EE;
            const float* wz_x = wih + (size_t)(j + HH)     * EE;
            const float* wn_x = wih + (size_t)(j + 2 * HH) * EE;
            #pragma unroll
            for (int q = 0; q < 4; ++q) {
                const int k = ks * 16 + q * 4;
                float4 wr = ldf4(wr_x + k), wz = ldf4(wz_x + k), wn = ldf4(wn_x + k);
                float x0 = xls[(k + 0) * 32 + b], x1 = xls[(k + 1) * 32 + b];
                float x2 = xls[(k + 2) * 32 + b], x3 = xls[(k + 3) * 32 + b];
                sR = fmaf(wr.x, x0, fmaf(wr.y, x1, fmaf(wr.z, x2, fmaf(wr.w, x3, sR))));
                sZ = fmaf(wz.x, x0, fmaf(wz.y, x1, fmaf(wz.z, x2, fmaf(wz.w, x3, sZ))));
                sI = fmaf(wn.x, x0, fmaf(wn.y, x1, fmaf(wn.z, x2, fmaf(wn.w, x3, sI))));
            }
            float* pd = &partD[ks][b * 2 + jl][0];
            pd[0] = sR; pd[1] = sZ; pd[2] = sN; pd[3] = sI;
        }
        __syncthreads();
        if (tid < 64) {
            const int b = tid >> 1, jl = tid & 1;
            const int j = bid * 2 + jl;
            float sR = bR, sZ = bZ, sN = bN, sI = bI;
            #pragma unroll
            for (int q2 = 0; q2 < 16; ++q2) {
                sR += partD[q2][tid][0]; sZ += partD[q2][tid][1];
                sN += partD[q2][tid][2]; sI += partD[q2][tid][3];
            }
            const float r = sigmoidf_(sR);
            const float z = sigmoidf_(sZ);
            const float n = tanhf(sI + r * sN);
            const float hold = hlds[j * 32 + b];
            cst4(hdG + (size_t)j * 32 + b, (1.0f - z) * n + z * hold);
        }

        gbar(flagD, bid, 256, tid, (unsigned)(2 * t + 1));

        // ---- stage h_t (coherent) -> hlds ----
        {
            const ull* hU = (const ull*)hdG;
            ull hv[8];
            #pragma unroll
            for (int i = 0; i < 8; ++i) hv[i] = cld8(hU + tid * 8 + i);
            ull* hlU = (ull*)hlds;
            #pragma unroll
            for (int i = 0; i < 8; ++i) hlU[tid * 8 + i] = hv[i];
        }
        __syncthreads();

        // ---- Phase B: logits, 4v x 4b x 4ks per thread ----
        {
            const int wave = tid >> 6, lane = tid & 63;
            const int bh = lane & 7, ks = (lane >> 3) & 3, vh = lane >> 5;
            const int voff = wave * 8 + vh * 4;          // 0..127
            const int vb   = bid * 125;
            const int k0   = ks * 128;

            const int o0 = voff,     o1 = voff + 1;
            const int o2 = voff + 2, o3 = voff + 3;
            const int v0 = vb + (o0 < 125 ? o0 : 124);
            const int v1 = vb + (o1 < 125 ? o1 : 124);
            const int v2 = vb + (o2 < 125 ? o2 : 124);
            const int v3 = vb + (o3 < 125 ? o3 : 124);
            const float* w0p = fc_w + (size_t)v0 * HH;
            const float* w1p = fc_w + (size_t)v1 * HH;
            const float* w2p = fc_w + (size_t)v2 * HH;
            const float* w3p = fc_w + (size_t)v3 * HH;

            float4 acc0 = {0,0,0,0}, acc1 = {0,0,0,0};
            float4 acc2 = {0,0,0,0}, acc3 = {0,0,0,0};

            for (int kk = 0; kk < 128; kk += 4) {
                const int k = k0 + kk;
                float4 w0 = ldf4(w0p + k), w1 = ldf4(w1p + k);
                float4 w2 = ldf4(w2p + k), w3 = ldf4(w3p + k);
                const float* hb = hlds + k * 32 + bh * 4;
                float4 h0 = ldf4(hb), h1 = ldf4(hb + 32);
                float4 h2 = ldf4(hb + 64), h3 = ldf4(hb + 96);
                fma4(acc0, w0.x, h0); fma4(acc0, w0.y, h1); fma4(acc0, w0.z, h2); fma4(acc0, w0.w, h3);
                fma4(acc1, w1.x, h0); fma4(acc1, w1.y, h1); fma4(acc1, w1.z, h2); fma4(acc1, w1.w, h3);
                fma4(acc2, w2.x, h0); fma4(acc2, w2.y, h1); fma4(acc2, w2.z, h2); fma4(acc2, w2.w, h3);
                fma4(acc3, w3.x, h0); fma4(acc3, w3.y, h1); fma4(acc3, w3.z, h2); fma4(acc3, w3.w, h3);
            }
            // reduce over ks (lane bits 3-4)
            XR4(acc0, 8); XR4(acc0, 16);
            XR4(acc1, 8); XR4(acc1, 16);
            XR4(acc2, 8); XR4(acc2, 16);
            XR4(acc3, 8); XR4(acc3, 16);

            const int b0 = bh * 4;
            ull kb0 = 0, kb1 = 0, kb2 = 0, kb3 = 0;
            #pragma unroll
            for (int i = 0; i < 4; ++i) {
                const int off = voff + i;
                if (off < 125) {
                    const int v = vb + off;
                    float4 a = (i == 0) ? acc0 : (i == 1) ? acc1
                             : (i == 2) ? acc2 : acc3;
                    const float fb = fc_b[v];
                    a.x += fb; a.y += fb; a.z += fb; a.w += fb;
                    if (ks == 0) {
                        out[((size_t)((b0 + 0) * TT + t)) * VV + v] = a.x;
                        out[((size_t)((b0 + 1) * TT + t)) * VV + v] = a.y;
                        out[((size_t)((b0 + 2) * TT + t)) * VV + v] = a.z;
                        out[((size_t)((b0 + 3) * TT + t)) * VV + v] = a.w;
                    }
                    ull t0 = mkkey(a.x, v); if (t0 > kb0) kb0 = t0;
                    ull t1 = mkkey(a.y, v); if (t1 > kb1) kb1 = t1;
                    ull t2 = mkkey(a.z, v); if (t2 > kb2) kb2 = t2;
                    ull t3 = mkkey(a.w, v); if (t3 > kb3) kb3 = t3;
                }
            }
            // reduce over vh (lane bit 5)
            kb0 = sxmax(kb0, 32); kb1 = sxmax(kb1, 32);
            kb2 = sxmax(kb2, 32); kb3 = sxmax(kb3, 32);
            if (lane < 8) {   // ks==0, vh==0
                lwred[wave][bh][0] = kb0; lwred[wave][bh][1] = kb1;
                lwred[wave][bh][2] = kb2; lwred[wave][bh][3] = kb3;
            }
        }
        __syncthreads();
        if (tid < 32) {
            ull km = lwred[0][tid >> 2][tid & 3];
            #pragma unroll
            for (int w2 = 1; w2 < 16; ++w2) {
                ull k2 = lwred[w2][tid >> 2][tid & 3];
                if (k2 > km) km = k2;
            }
            __hip_atomic_store(cand + (size_t)bid * 32 + tid, km,
                               __ATOMIC_RELAXED, __HIP_MEMORY_SCOPE_AGENT);
        }

        if (t < TT - 1)
            gbar(flagD, bid, 256, tid, (unsigned)(2 * t + 2));
    }
}

// ---------------------------------------------------------------------------
extern "C" void kernel_launch(void* const* d_in, const int* in_sizes, int n_in,
                              void* d_out, int out_size, void* d_ws, size_t ws_size,
                              hipStream_t stream) {
    (void)in_sizes; (void)n_in; (void)out_size; (void)ws_size;

    const int*   body    = (const int*)  d_in[0];
    const float* enc_emb = (const float*)d_in[2];
    const float* wih_f   = (const float*)d_in[3];
    const float* whh_f   = (const float*)d_in[4];
    const float* bih_f   = (const float*)d_in[5];
    const float* bhh_f   = (const float*)d_in[6];
    const float* wih_b   = (const float*)d_in[7];
    const float* whh_b   = (const float*)d_in[8];
    const float* bih_b   = (const float*)d_in[9];
    const float* bhh_b   = (const float*)d_in[10];
    const float* dec_emb = (const float*)d_in[11];
    const float* dwih    = (const float*)d_in[12];
    const float* dwhh    = (const float*)d_in[13];
    const float* dbih    = (const float*)d_in[14];
    const float* dbhh    = (const float*)d_in[15];
    const float* fc_w    = (const float*)d_in[16];
    const float* fc_b    = (const float*)d_in[17];
    float* out = (float*)d_out;

    char* ws = (char*)d_ws;
    float* hD    = (float*)(ws);                    // [8][2][512][8] = 262,144 B
    float* hdT   = (float*)(ws + 262144);           // [512][32]      =  65,536 B
    float* hdG   = (float*)(ws + 327680);           // [512][32]      =  65,536 B
    ull*   cand  = (ull*)  (ws + 393216);           // [256][32]      =  65,536 B
    unsigned* flagE = (unsigned*)(ws + 458752);     // 8*32*128 B     =  32,768 B
    unsigned* flagD = (unsigned*)(ws + 491520);     // 256*128 B      =  32,768 B

    // re-init cross-call state (graph-replay safe)
    (void)hipMemsetAsync(hD, 0, 262144, stream);
    (void)hipMemsetAsync(flagE, 0, 65536, stream);  // flagE + flagD contiguous

    enc_persist3<<<256, 256, 0, stream>>>(
        body, enc_emb, wih_f, whh_f, bih_f, bhh_f,
        wih_b, whh_b, bih_b, bhh_b, hD, flagE);

    enc_fin<<<64, 256, 0, stream>>>(hD, hdT);

    dec_persist3<<<256, 1024, 0, stream>>>(
        dec_emb, dwih, dwhh, dbih, dbhh, fc_w, fc_b,
        hdT, hdG, cand, out, flagD);
}